// Round 5
// baseline (128.531 us; speedup 1.0000x reference)
//
#include <hip/hip_runtime.h>
#include <hip/hip_bf16.h>

constexpr int BATCH = 4;
constexpr int SEQ   = 1024;
constexpr int DM    = 512;     // model dim = HEADS*HDIM
constexpr int NH    = 8;
constexpr int HD    = 64;
constexpr int NQKV  = 1536;    // q(512) + k(512) + v(512) fused projection width

typedef unsigned short u16;
typedef __attribute__((ext_vector_type(8))) __bf16 bf8;
typedef __attribute__((ext_vector_type(4))) __bf16 bf4;
typedef __attribute__((ext_vector_type(4))) float  f4;
typedef __attribute__((ext_vector_type(16))) float f16v;

#define MFMA16(a, b, c) __builtin_amdgcn_mfma_f32_16x16x32_bf16(a, b, c, 0, 0, 0)
#define MFMA32(a, b, c) __builtin_amdgcn_mfma_f32_32x32x16_bf16(a, b, c, 0, 0, 0)

// 0.125 (1/sqrt(64)) * log2(e): q pre-scale so softmax uses exp2 directly
#define QSC 0.18033688f

static __device__ __forceinline__ u16 f2b(float f) {
    union { float f; unsigned u; } v; v.f = f;
    unsigned r = v.u + 0x7FFFu + ((v.u >> 16) & 1u);   // RNE; inputs never NaN
    return (u16)(r >> 16);
}
static __device__ __forceinline__ float b2f(u16 x) {
    union { unsigned u; float f; } v; v.u = (unsigned)x << 16;   // bf16->f32 exact
    return v.f;
}
static __device__ __forceinline__ float fexp2(float x) {
    return __builtin_amdgcn_exp2f(x);
}
// async global->LDS, 16 B per lane (dst = wave-uniform base + lane*16; the
// GLOBAL source address is per-lane, which is what makes source-side
// swizzling possible)
static __device__ __forceinline__ void gl_lds16(const void* g, void* l) {
    __builtin_amdgcn_global_load_lds(
        (const __attribute__((address_space(1))) void*)g,
        (__attribute__((address_space(3))) void*)l, 16, 0, 0);
}
// pack two f32 -> one u32 of 2 bf16 (RNE), single VOP3
static __device__ __forceinline__ unsigned cvtpk_bf16(float lo, float hi) {
    unsigned r;
    asm("v_cvt_pk_bf16_f32 %0, %1, %2" : "=v"(r) : "v"(lo), "v"(hi));
    return r;
}
// swap a's hi-32-lane half with b's lo-32-lane half
static __device__ __forceinline__ void swap32(unsigned &a, unsigned &b) {
    asm("v_permlane32_swap_b32 %0, %1" : "+v"(a), "+v"(b));
}

// ---------------------------------------------------------------------------
// Fused prep: one launch does all fp32->bf16 converts + weight transposes.
// ---------------------------------------------------------------------------
__device__ __forceinline__ void tcvt_tile(const float* __restrict__ in,
                                          u16* __restrict__ out,
                                          int R, int C, int bx, int by, int tid,
                                          float (*t)[33]) {
    int r0 = by * 32, c0 = bx * 32;
    int lc = tid & 31, lr = tid >> 5;   // lr in [0,8)
    #pragma unroll
    for (int p = 0; p < 4; p++) {
        int r = lr + p * 8;
        t[r][lc] = in[(size_t)(r0 + r) * C + c0 + lc];
    }
    __syncthreads();
    #pragma unroll
    for (int p = 0; p < 4; p++) {
        int r = lr + p * 8;
        out[(size_t)(c0 + r) * R + r0 + lc] = f2b(t[lc][r]);
    }
}

__global__ __launch_bounds__(256)
void prep(const float* __restrict__ x, const float* __restrict__ Wq,
          const float* __restrict__ Wkv, const float* __restrict__ Wout,
          const float* __restrict__ pemb,
          u16* __restrict__ xb, u16* __restrict__ qkvw,
          u16* __restrict__ Woutt, u16* __restrict__ pembb) {
    __shared__ float t[32][33];
    const int blk = blockIdx.x, tid = threadIdx.x;
    if (blk < 2048) {
        int i = (blk * 256 + tid) * 4;
        float4 v = *(const float4*)(x + i);
        ushort4 o = {f2b(v.x), f2b(v.y), f2b(v.z), f2b(v.w)};
        *(ushort4*)(xb + i) = o;
    } else if (blk < 2113) {
        int i = ((blk - 2048) * 256 + tid) * 4;
        if (i < 1025 * HD) {
            float4 v = *(const float4*)(pemb + i);
            ushort4 o = {f2b(v.x), f2b(v.y), f2b(v.z), f2b(v.w)};
            *(ushort4*)(pembb + i) = o;
        }
    } else if (blk < 2369) {
        int l = blk - 2113;
        tcvt_tile(Wq, qkvw, 512, 512, l & 15, l >> 4, tid, t);
    } else if (blk < 2881) {
        int l = blk - 2369;
        tcvt_tile(Wkv, qkvw + 512 * 512, 512, 1024, l & 31, l >> 5, tid, t);
    } else {
        int l = blk - 2881;
        tcvt_tile(Wout, Woutt, 512, 512, l & 15, l >> 4, tid, t);
    }
}

// ---------------------------------------------------------------------------
// MFMA GEMM: C[M,N] = A[M,K] @ Bt[N,K]^T  (bf16 in, fp32 acc)
// Templated on BN (tile = 64 x BN). BK=64 as 2x 32-wide sub-tiles (m97
// layout). 256 threads = 4 waves; per-wave output 32 x BN/2.
//   BN=128: QKV projection (grid-rich, 2-3 blocks/CU).
//   BN=64:  output projection — N=512 gave only 256 blocks = 1 block/CU at
//           BN=128; BN=64 doubles the grid to 512 = 2 blocks/CU.
// Mode 1 (Cf!=null): fp32 out + bias. Mode 2 (qtb/ktb/vtb): QKV packing.
// ---------------------------------------------------------------------------
template<int BN>
__global__ __launch_bounds__(256)
void gemm_bt(const u16* __restrict__ A, const u16* __restrict__ Bt,
             int M, int N, int K,
             float* __restrict__ Cf, const float* __restrict__ bias,
             __bf16* __restrict__ qtb, __bf16* __restrict__ ktb,
             __bf16* __restrict__ vtb) {
    constexpr int NJ = BN / 32;          // B-frags per wave
    __shared__ __align__(16) u16 As[2][64][32];
    __shared__ __align__(16) u16 Bs[2][BN][32];
    const int tid = threadIdx.x, w = tid >> 6, lane = tid & 63;
    const int l15 = lane & 15, l4 = lane >> 4;
    const int wr = (w >> 1) * 32, wc = (w & 1) * (BN / 2);
    const int bm = blockIdx.y * 64, bn = blockIdx.x * BN;

    f4 acc[2][NJ];
    #pragma unroll
    for (int i = 0; i < 2; i++)
        #pragma unroll
        for (int j = 0; j < NJ; j++) acc[i][j] = (f4){0.f, 0.f, 0.f, 0.f};

    const int rS = lane >> 2;          // row within a 16-row staging group
    const int cS = (lane & 3) * 8;     // col (u16) within the 32-wide row

    for (int k0 = 0; k0 < K; k0 += 64) {
        #pragma unroll
        for (int ks = 0; ks < 2; ks++) {
            // A: sub-tile ks, rows [w*16, +16)
            gl_lds16(A + (size_t)(bm + w * 16 + rS) * K + k0 + ks * 32 + cS,
                     &As[ks][w * 16][0]);
            // B: sub-tile ks, BN/4 rows per wave in 16-row groups
            #pragma unroll
            for (int rb = 0; rb < BN / 4; rb += 16)
                gl_lds16(Bt + (size_t)(bn + w * (BN / 4) + rb + rS) * K
                             + k0 + ks * 32 + cS,
                         &Bs[ks][w * (BN / 4) + rb][0]);
        }
        __syncthreads();
        #pragma unroll
        for (int ks = 0; ks < 2; ks++) {
            bf8 af[2], bf[NJ];
            #pragma unroll
            for (int i = 0; i < 2; i++)
                af[i] = *(const bf8*)&As[ks][wr + i * 16 + l15][l4 * 8];
            #pragma unroll
            for (int j = 0; j < NJ; j++)
                bf[j] = *(const bf8*)&Bs[ks][wc + j * 16 + l15][l4 * 8];
            #pragma unroll
            for (int i = 0; i < 2; i++)
                #pragma unroll
                for (int j = 0; j < NJ; j++)
                    acc[i][j] = MFMA16(af[i], bf[j], acc[i][j]);
        }
        __syncthreads();
    }
    #pragma unroll
    for (int i = 0; i < 2; i++)
        #pragma unroll
        for (int j = 0; j < NJ; j++) {
            const int col = bn + wc + j * 16 + l15;
            const int row0 = bm + wr + i * 16 + l4 * 4;
            if (Cf) {
                #pragma unroll
                for (int reg = 0; reg < 4; reg++)
                    Cf[(size_t)(row0 + reg) * N + col] = acc[i][j][reg] + bias[col];
            } else if (col < 512) {
                int h = col >> 6, d = col & 63;
                #pragma unroll
                for (int reg = 0; reg < 4; reg++) {
                    int row = row0 + reg;
                    int b = row >> 10, t = row & 1023;
                    qtb[((((size_t)(b * 8 + h)) << 10 | t) << 6) | d] =
                        (__bf16)(acc[i][j][reg] * QSC);
                }
            } else if (col < 1024) {
                int h = (col >> 6) - 8, d = col & 63;
                #pragma unroll
                for (int reg = 0; reg < 4; reg++) {
                    int row = row0 + reg;
                    int b = row >> 10, t = row & 1023;
                    ktb[((((size_t)(b * 8 + h)) << 10 | t) << 6) | d] =
                        (__bf16)acc[i][j][reg];
                }
            } else {
                int h = (col >> 6) - 16, d = col & 63;
                int b = row0 >> 10, t = row0 & 1023;   // 4 rows share b (t aligned 4)
                __bf16 pk[4];
                #pragma unroll
                for (int reg = 0; reg < 4; reg++) pk[reg] = (__bf16)acc[i][j][reg];
                *(ushort4*)&vtb[(((size_t)(b * 8 + h) * 64 + d) << 10) | t] =
                    *(ushort4*)pk;
            }
        }
}

// ---------------------------------------------------------------------------
// Fused MFMA flash attention — 32x32 quadrant structure (R3/R4) + DMA-direct
// K/V staging (R5). R4 analysis: the reg-staging round-trip (4 global->VGPR
// loads carried a full iteration + 4 ds_write_b128 commits on the pre-barrier
// tail) is pure redistribution overhead — 8 instr/thread/iter + 16 VGPRs +
// 4 KB/wave-iter of LDS write traffic. Replaced with global_load_lds (m151:
// DMA staging > reg staging) using the T2/m173 both-sides XOR swizzle:
//  - LDS K/V tiles are LINEAR [64][64] (gl_lds16 needs dst = base+lane*16);
//    the 16B granule index is swizzled on the GLOBAL SOURCE address
//    (g ^= row&7) and identically on the read side. Verified conflict-free:
//    frag reads land 8 lanes per 4-bank group (linear unswizzled would be
//    32-way; the old [72]-pad layout can't be DMA'd).
//  - 4 gl_lds16 per wave per iter, issued at iteration top (full iteration
//    before use -> the barrier's automatic vmcnt(0) drain is free).
// Everything else unchanged: swapped QK^T (lane-local softmax), cvt_pk +
// permlane32 P->A-frags (no LDS round-trip), LDS qdot ring [j&255][s] with
// b64 refresh writes, softmax/PV interleave, setprio around MFMA cluster,
// one barrier per K-tile. Grid: x = bh (XCD L2 locality), y = s0/64.
// LDS = 69,632 B -> 2 blocks/CU (grid-capped anyway).
// ---------------------------------------------------------------------------
__global__ __launch_bounds__(256)
void attn_mfma(const u16* __restrict__ qtb, const u16* __restrict__ ktb,
               const u16* __restrict__ vtb, const u16* __restrict__ pembb,
               __bf16* __restrict__ ctxb) {
    __shared__ __align__(16) __bf16 Kb[2][64][64];  // K tiles [t][d], swz granules
    __shared__ __align__(16) __bf16 Vb[2][64][64];  // V tiles [d][t], swz granules
    __shared__ __align__(16) __bf16 Qd[256][72];    // qdot ring [j&255][s]

    const int tid = threadIdx.x, w = tid >> 6, lane = tid & 63;
    const int l31 = lane & 31, hi = lane >> 5;
    const int wq = w >> 1, wt = w & 1;
    const int bh = blockIdx.x, b = bh >> 3;
    const int s0 = blockIdx.y * 64;
    const int m7 = l31 & 7;                 // read-side swizzle key (row&7)

    // staging lane mapping: row-in-8-group = lane>>3, granule = lane&7;
    // swizzled source u16 offset within the 128B row:
    const int srow = lane >> 3;             // 0..7
    const int sswz = ((lane & 7) ^ srow) * 8;

    // Q frags (B-operand for swapped QK^T, A-operand for ring refresh)
    bf8 qb[4];
    {
        const u16* qp = qtb + ((size_t)bh * SEQ + s0 + wq * 32 + l31) * HD + hi * 8;
        #pragma unroll
        for (int st = 0; st < 4; st++) qb[st] = *(const bf8*)(qp + st * 16);
    }

    // ---- init ring: j in [s0+449, +127], wave covers (s=wq-half, j=wt-half)
    #pragma unroll
    for (int pass = 0; pass < 2; pass++) {
        const int jr = s0 + 449 + pass * 64 + wt * 32 + l31;
        const int jc = min(1024, max(0, jr));
        const u16* pp = pembb + (size_t)jc * HD + hi * 8;
        f16v acc;
        #pragma unroll
        for (int r = 0; r < 16; r++) acc[r] = 0.f;
        #pragma unroll
        for (int st = 0; st < 4; st++) {
            bf8 pj = *(const bf8*)(pp + st * 16);
            acc = MFMA32(qb[st], pj, acc);
        }
        #pragma unroll
        for (int o4 = 0; o4 < 4; o4++) {
            bf4 pk;
            #pragma unroll
            for (int r = 0; r < 4; r++) pk[r] = (__bf16)acc[o4 * 4 + r];
            *(bf4*)&Qd[jr & 255][wq * 32 + o4 * 8 + hi * 4] = pk;
        }
    }

    float l_lane = 0.f;
    f16v oo[2];
    #pragma unroll
    for (int dt = 0; dt < 2; dt++)
        #pragma unroll
        for (int r = 0; r < 16; r++) oo[dt][r] = 0.f;

    const u16* kbase = ktb + (size_t)bh * SEQ * HD;   // [t][d] packed
    const u16* vbase = vtb + (size_t)bh * HD * SEQ;   // [d][t]

    // ---- stage tile 0 into buf 0 (async DMA, swizzled source) ----
    #pragma unroll
    for (int G = 0; G < 2; G++) {
        const int r0 = w * 16 + G * 8;
        gl_lds16(kbase + (size_t)(r0 + srow) * HD + sswz, &Kb[0][r0][0]);
        gl_lds16(vbase + (size_t)(r0 + srow) * SEQ + sswz, &Vb[0][r0][0]);
    }
    __syncthreads();

    for (int i = 0; i < 16; i++) {
        const int cur = i & 1, nxt = cur ^ 1;
        const int t0 = i * 64, t1 = t0 + 64;
        const bool pre = (i < 15);
        // ---- issue next tile's staging (DMA) + pemb reg loads ----
        bf8 pj0, pj1, pj2, pj3;
        const int jrn = s0 + 449 - 64 * (i + 1) + wt * 32 + l31;
        if (pre) {
            #pragma unroll
            for (int G = 0; G < 2; G++) {
                const int r0 = w * 16 + G * 8;
                gl_lds16(kbase + (size_t)(t1 + r0 + srow) * HD + sswz,
                         &Kb[nxt][r0][0]);
                gl_lds16(vbase + (size_t)(r0 + srow) * SEQ + t1 + sswz,
                         &Vb[nxt][r0][0]);
            }
            const int jc = min(1024, max(0, jrn));
            const u16* pp = pembb + (size_t)jc * HD + hi * 8;
            pj0 = *(const bf8*)(pp);
            pj1 = *(const bf8*)(pp + 16);
            pj2 = *(const bf8*)(pp + 32);
            pj3 = *(const bf8*)(pp + 48);
        }

        // ---- ALL LDS loads up front: K-frags, ring gather, V-frags ----
        bf8 ka[4];
        #pragma unroll
        for (int st = 0; st < 4; st++)
            ka[st] = *(const bf8*)&Kb[cur][wt * 32 + l31][((st * 2 + hi) ^ m7) * 8];
        const int jcst = (s0 - t0 + 512) + wq * 32 + l31 - wt * 32 - 4 * hi;
        const u16* qdc = (const u16*)&Qd[0][0] + wq * 32 + l31;
        u16 rg[16];
        #pragma unroll
        for (int r = 0; r < 16; r++) {
            const int pat = (r & 3) + 8 * (r >> 2);
            rg[r] = qdc[((jcst - pat) & 255) * 72];
        }
        bf8 vf00 = *(const bf8*)&Vb[cur][l31][((wt * 4 + hi) ^ m7) * 8];
        bf8 vf01 = *(const bf8*)&Vb[cur][l31][((wt * 4 + 2 + hi) ^ m7) * 8];
        bf8 vf10 = *(const bf8*)&Vb[cur][32 + l31][((wt * 4 + hi) ^ m7) * 8];
        bf8 vf11 = *(const bf8*)&Vb[cur][32 + l31][((wt * 4 + 2 + hi) ^ m7) * 8];

        __builtin_amdgcn_s_setprio(1);
        // ---- QK^T, swapped: lane holds q = wq*32+l31, 16 t's of wt-half ----
        f16v s16;
        #pragma unroll
        for (int r = 0; r < 16; r++) s16[r] = 0.f;
        #pragma unroll
        for (int st = 0; st < 4; st++) s16 = MFMA32(ka[st], qb[st], s16);

        // ---- softmax half 0 -> pa0 -> 2 PV MFMAs ----
        float p[16];
        float la = 0.f, lb = 0.f;
        #pragma unroll
        for (int r = 0; r < 8; r++) {
            float pv = fexp2(s16[r] + b2f(rg[r]));
            p[r] = pv; la += pv;
        }
        unsigned w00 = cvtpk_bf16(p[0], p[1]), w01 = cvtpk_bf16(p[2], p[3]);
        unsigned w10 = cvtpk_bf16(p[4], p[5]), w11 = cvtpk_bf16(p[6], p[7]);
        swap32(w00, w10); swap32(w01, w11);
        union { unsigned u[4]; bf8 v; } pa0, pa1;
        pa0.u[0] = w00; pa0.u[1] = w01; pa0.u[2] = w10; pa0.u[3] = w11;
        oo[0] = MFMA32(pa0.v, vf00, oo[0]);
        oo[1] = MFMA32(pa0.v, vf10, oo[1]);
        // ---- softmax half 1 -> pa1 -> 2 PV MFMAs ----
        #pragma unroll
        for (int r = 8; r < 16; r++) {
            float pv = fexp2(s16[r] + b2f(rg[r]));
            p[r] = pv; lb += pv;
        }
        unsigned w20 = cvtpk_bf16(p[8],  p[9]),  w21 = cvtpk_bf16(p[10], p[11]);
        unsigned w30 = cvtpk_bf16(p[12], p[13]), w31 = cvtpk_bf16(p[14], p[15]);
        swap32(w20, w30); swap32(w21, w31);
        pa1.u[0] = w20; pa1.u[1] = w21; pa1.u[2] = w30; pa1.u[3] = w31;
        oo[0] = MFMA32(pa1.v, vf01, oo[0]);
        oo[1] = MFMA32(pa1.v, vf11, oo[1]);
        __builtin_amdgcn_s_setprio(0);
        l_lane += la + lb;

        // ---- ring refresh for next window (pemb frags already in regs) ----
        if (pre) {
            f16v rf;
            #pragma unroll
            for (int r = 0; r < 16; r++) rf[r] = 0.f;
            rf = MFMA32(qb[0], pj0, rf);
            rf = MFMA32(qb[1], pj1, rf);
            rf = MFMA32(qb[2], pj2, rf);
            rf = MFMA32(qb[3], pj3, rf);
            #pragma unroll
            for (int o4 = 0; o4 < 4; o4++) {
                bf4 pk;
                #pragma unroll
                for (int r = 0; r < 4; r++) pk[r] = (__bf16)rf[o4 * 4 + r];
                *(bf4*)&Qd[jrn & 255][wq * 32 + o4 * 8 + hi * 4] = pk;
            }
        }
        __syncthreads();   // staging DMA drained + visible; buffers released
    }

    // ---- epilogue: cross-half l, cross-wave O reduce (ring LDS reused),
    //      normalize, store ----
    float lsum = l_lane + __shfl_xor(l_lane, 32);
    float* Os = (float*)&Qd[0][0];          // ring is dead; reuse as scratch
    float* Ls = Os + 4096;
    if (lane < 32) Ls[(wq * 2 + wt) * 32 + l31] = lsum;
    if (wt == 0) {
        #pragma unroll
        for (int dt = 0; dt < 2; dt++)
            #pragma unroll
            for (int r = 0; r < 16; r++) {
                const int q = (r & 3) + 8 * (r >> 2) + 4 * hi;
                Os[(wq * 32 + q) * 64 + dt * 32 + l31] = oo[dt][r];
            }
    }
    __syncthreads();
    if (wt == 1) {
        const int h = bh & 7;
        #pragma unroll
        for (int r = 0; r < 16; r++) {
            const int q = (r & 3) + 8 * (r >> 2) + 4 * hi;
            const float li = 1.f / (Ls[wq * 64 + q] + Ls[wq * 64 + 32 + q]);
            #pragma unroll
            for (int dt = 0; dt < 2; dt++) {
                float v = (oo[dt][r] + Os[(wq * 32 + q) * 64 + dt * 32 + l31]) * li;
                ctxb[(size_t)(b * SEQ + s0 + wq * 32 + q) * DM + h * HD + dt * 32 + l31]
                    = (__bf16)v;
            }
        }
    }
}

// ---------------------------------------------------------------------------
extern "C" void kernel_launch(void* const* d_in, const int* in_sizes, int n_in,
                              void* d_out, int out_size, void* d_ws, size_t ws_size,
                              hipStream_t stream) {
    const float* x    = (const float*)d_in[0];
    // d_in[1] attn_mask: unused by the reference computation
    const float* Wq   = (const float*)d_in[2];
    const float* Wkv  = (const float*)d_in[3];
    const float* Wout = (const float*)d_in[4];
    const float* bout = (const float*)d_in[5];
    const float* pemb = (const float*)d_in[6];
    float* out = (float*)d_out;

    const int M = BATCH * SEQ;   // 4096
    u16* p = (u16*)d_ws;
    u16* xb    = p; p += (size_t)M * DM;          // 4096x512
    u16* qkvw  = p; p += (size_t)NQKV * DM;       // 1536x512 (Wq^T ++ Wkv^T)
    u16* Woutt = p; p += (size_t)DM * DM;         // 512x512
    u16* pembb = p; p += (size_t)1025 * HD;       // 1025x64
    u16* qtb   = p; p += (size_t)M * DM;          // 32x1024x64 packed q (scaled)
    u16* ktb   = p; p += (size_t)M * DM;          // 32x1024x64 packed K
    u16* vtb   = p; p += (size_t)M * DM;          // 32x64x1024 transposed V
    u16* ctxb  = p; p += (size_t)M * DM;          // 4096x512

    prep<<<3137, 256, 0, stream>>>(x, Wq, Wkv, Wout, pemb, xb, qkvw, Woutt, pembb);

    // QKV projection with fused q-scale / K-pack / V-transpose epilogue
    gemm_bt<128><<<dim3(NQKV / 128, M / 64), 256, 0, stream>>>(
        xb, qkvw, M, NQKV, DM, nullptr, nullptr,
        (__bf16*)qtb, (__bf16*)ktb, (__bf16*)vtb);

    // fused attention -> ctx; grid x=bh for XCD L2 locality
    attn_mfma<<<dim3(BATCH * NH, SEQ / 64), 256, 0, stream>>>(
        qtb, ktb, vtb, pembb, (__bf16*)ctxb);

    // out = ctx @ Wout + bout  (BN=64: 512 blocks = 2/CU vs 1/CU at BN=128)
    gemm_bt<64><<<dim3(DM / 64, M / 64), 256, 0, stream>>>(
        ctxb, Woutt, M, DM, DM, out, bout, nullptr, nullptr, nullptr);
}

// Round 6
// 125.962 us; speedup vs baseline: 1.0204x; 1.0204x over previous
//
#include <hip/hip_runtime.h>
#include <hip/hip_bf16.h>

constexpr int BATCH = 4;
constexpr int SEQ   = 1024;
constexpr int DM    = 512;     // model dim = HEADS*HDIM
constexpr int NH    = 8;
constexpr int HD    = 64;
constexpr int NQKV  = 1536;    // q(512) + k(512) + v(512) fused projection width

typedef unsigned short u16;
typedef __attribute__((ext_vector_type(8))) __bf16 bf8;
typedef __attribute__((ext_vector_type(4))) __bf16 bf4;
typedef __attribute__((ext_vector_type(4))) float  f4;
typedef __attribute__((ext_vector_type(16))) float f16v;

#define MFMA16(a, b, c) __builtin_amdgcn_mfma_f32_16x16x32_bf16(a, b, c, 0, 0, 0)
#define MFMA32(a, b, c) __builtin_amdgcn_mfma_f32_32x32x16_bf16(a, b, c, 0, 0, 0)

// 0.125 (1/sqrt(64)) * log2(e): q pre-scale so softmax uses exp2 directly
#define QSC 0.18033688f

static __device__ __forceinline__ u16 f2b(float f) {
    union { float f; unsigned u; } v; v.f = f;
    unsigned r = v.u + 0x7FFFu + ((v.u >> 16) & 1u);   // RNE; inputs never NaN
    return (u16)(r >> 16);
}
static __device__ __forceinline__ float b2f(u16 x) {
    union { unsigned u; float f; } v; v.u = (unsigned)x << 16;   // bf16->f32 exact
    return v.f;
}
static __device__ __forceinline__ float fexp2(float x) {
    return __builtin_amdgcn_exp2f(x);
}
// async global->LDS, 16 B per lane (dst = wave-uniform base + lane*16)
static __device__ __forceinline__ void gl_lds16(const void* g, void* l) {
    __builtin_amdgcn_global_load_lds(
        (const __attribute__((address_space(1))) void*)g,
        (__attribute__((address_space(3))) void*)l, 16, 0, 0);
}
// pack two f32 -> one u32 of 2 bf16 (RNE), single VOP3
static __device__ __forceinline__ unsigned cvtpk_bf16(float lo, float hi) {
    unsigned r;
    asm("v_cvt_pk_bf16_f32 %0, %1, %2" : "=v"(r) : "v"(lo), "v"(hi));
    return r;
}
// swap a's hi-32-lane half with b's lo-32-lane half
static __device__ __forceinline__ void swap32(unsigned &a, unsigned &b) {
    asm("v_permlane32_swap_b32 %0, %1" : "+v"(a), "+v"(b));
}

// ---------------------------------------------------------------------------
// Fused prep: one launch does all fp32->bf16 converts + weight transposes.
// ---------------------------------------------------------------------------
__device__ __forceinline__ void tcvt_tile(const float* __restrict__ in,
                                          u16* __restrict__ out,
                                          int R, int C, int bx, int by, int tid,
                                          float (*t)[33]) {
    int r0 = by * 32, c0 = bx * 32;
    int lc = tid & 31, lr = tid >> 5;   // lr in [0,8)
    #pragma unroll
    for (int p = 0; p < 4; p++) {
        int r = lr + p * 8;
        t[r][lc] = in[(size_t)(r0 + r) * C + c0 + lc];
    }
    __syncthreads();
    #pragma unroll
    for (int p = 0; p < 4; p++) {
        int r = lr + p * 8;
        out[(size_t)(c0 + r) * R + r0 + lc] = f2b(t[lc][r]);
    }
}

__global__ __launch_bounds__(256)
void prep(const float* __restrict__ x, const float* __restrict__ Wq,
          const float* __restrict__ Wkv, const float* __restrict__ Wout,
          const float* __restrict__ pemb,
          u16* __restrict__ xb, u16* __restrict__ qkvw,
          u16* __restrict__ Woutt, u16* __restrict__ pembb) {
    __shared__ float t[32][33];
    const int blk = blockIdx.x, tid = threadIdx.x;
    if (blk < 2048) {
        int i = (blk * 256 + tid) * 4;
        float4 v = *(const float4*)(x + i);
        ushort4 o = {f2b(v.x), f2b(v.y), f2b(v.z), f2b(v.w)};
        *(ushort4*)(xb + i) = o;
    } else if (blk < 2113) {
        int i = ((blk - 2048) * 256 + tid) * 4;
        if (i < 1025 * HD) {
            float4 v = *(const float4*)(pemb + i);
            ushort4 o = {f2b(v.x), f2b(v.y), f2b(v.z), f2b(v.w)};
            *(ushort4*)(pembb + i) = o;
        }
    } else if (blk < 2369) {
        int l = blk - 2113;
        tcvt_tile(Wq, qkvw, 512, 512, l & 15, l >> 4, tid, t);
    } else if (blk < 2881) {
        int l = blk - 2369;
        tcvt_tile(Wkv, qkvw + 512 * 512, 512, 1024, l & 31, l >> 5, tid, t);
    } else {
        int l = blk - 2881;
        tcvt_tile(Wout, Woutt, 512, 512, l & 15, l >> 4, tid, t);
    }
}

// ---------------------------------------------------------------------------
// MFMA GEMM: C[M,N] = A[M,K] @ Bt[N,K]^T  (bf16 in, fp32 acc)
// Templated on BN (tile = 64 x BN). BK=64 as 2x 32-wide sub-tiles (m97
// layout). 256 threads = 4 waves; per-wave output 32 x BN/2.
//   BN=192: QKV projection — 12 MFMA per wave-substep vs 4 gl_lds16 staging
//           (A:1 + B:3, 48 rows/wave = 3 full 16-row groups). 1.5x arith
//           intensity over BN=128; grid 8x64 = 512 blocks = 2/CU.
//   BN=64:  output projection — 512 blocks = 2/CU (was 1/CU at BN=128).
// Mode 1 (Cf!=null): fp32 out + bias. Mode 2 (qtb/ktb/vtb): QKV packing
// (512/1024 col boundaries are multiples of 16, so straddling tiles are
// handled by the per-16-col-group branch).
// ---------------------------------------------------------------------------
template<int BN>
__global__ __launch_bounds__(256)
void gemm_bt(const u16* __restrict__ A, const u16* __restrict__ Bt,
             int M, int N, int K,
             float* __restrict__ Cf, const float* __restrict__ bias,
             __bf16* __restrict__ qtb, __bf16* __restrict__ ktb,
             __bf16* __restrict__ vtb) {
    constexpr int NJ = BN / 32;          // B-frags per wave
    __shared__ __align__(16) u16 As[2][64][32];
    __shared__ __align__(16) u16 Bs[2][BN][32];
    const int tid = threadIdx.x, w = tid >> 6, lane = tid & 63;
    const int l15 = lane & 15, l4 = lane >> 4;
    const int wr = (w >> 1) * 32, wc = (w & 1) * (BN / 2);
    const int bm = blockIdx.y * 64, bn = blockIdx.x * BN;

    f4 acc[2][NJ];
    #pragma unroll
    for (int i = 0; i < 2; i++)
        #pragma unroll
        for (int j = 0; j < NJ; j++) acc[i][j] = (f4){0.f, 0.f, 0.f, 0.f};

    const int rS = lane >> 2;          // row within a 16-row staging group
    const int cS = (lane & 3) * 8;     // col (u16) within the 32-wide row

    for (int k0 = 0; k0 < K; k0 += 64) {
        #pragma unroll
        for (int ks = 0; ks < 2; ks++) {
            // A: sub-tile ks, rows [w*16, +16)
            gl_lds16(A + (size_t)(bm + w * 16 + rS) * K + k0 + ks * 32 + cS,
                     &As[ks][w * 16][0]);
            // B: sub-tile ks, BN/4 rows per wave in 16-row groups
            #pragma unroll
            for (int rb = 0; rb < BN / 4; rb += 16)
                gl_lds16(Bt + (size_t)(bn + w * (BN / 4) + rb + rS) * K
                             + k0 + ks * 32 + cS,
                         &Bs[ks][w * (BN / 4) + rb][0]);
        }
        __syncthreads();
        #pragma unroll
        for (int ks = 0; ks < 2; ks++) {
            bf8 af[2], bf[NJ];
            #pragma unroll
            for (int i = 0; i < 2; i++)
                af[i] = *(const bf8*)&As[ks][wr + i * 16 + l15][l4 * 8];
            #pragma unroll
            for (int j = 0; j < NJ; j++)
                bf[j] = *(const bf8*)&Bs[ks][wc + j * 16 + l15][l4 * 8];
            #pragma unroll
            for (int i = 0; i < 2; i++)
                #pragma unroll
                for (int j = 0; j < NJ; j++)
                    acc[i][j] = MFMA16(af[i], bf[j], acc[i][j]);
        }
        __syncthreads();
    }
    #pragma unroll
    for (int i = 0; i < 2; i++)
        #pragma unroll
        for (int j = 0; j < NJ; j++) {
            const int col = bn + wc + j * 16 + l15;
            const int row0 = bm + wr + i * 16 + l4 * 4;
            if (Cf) {
                #pragma unroll
                for (int reg = 0; reg < 4; reg++)
                    Cf[(size_t)(row0 + reg) * N + col] = acc[i][j][reg] + bias[col];
            } else if (col < 512) {
                int h = col >> 6, d = col & 63;
                #pragma unroll
                for (int reg = 0; reg < 4; reg++) {
                    int row = row0 + reg;
                    int b = row >> 10, t = row & 1023;
                    qtb[((((size_t)(b * 8 + h)) << 10 | t) << 6) | d] =
                        (__bf16)(acc[i][j][reg] * QSC);
                }
            } else if (col < 1024) {
                int h = (col >> 6) - 8, d = col & 63;
                #pragma unroll
                for (int reg = 0; reg < 4; reg++) {
                    int row = row0 + reg;
                    int b = row >> 10, t = row & 1023;
                    ktb[((((size_t)(b * 8 + h)) << 10 | t) << 6) | d] =
                        (__bf16)acc[i][j][reg];
                }
            } else {
                int h = (col >> 6) - 16, d = col & 63;
                int b = row0 >> 10, t = row0 & 1023;   // 4 rows share b (t aligned 4)
                __bf16 pk[4];
                #pragma unroll
                for (int reg = 0; reg < 4; reg++) pk[reg] = (__bf16)acc[i][j][reg];
                *(ushort4*)&vtb[(((size_t)(b * 8 + h) * 64 + d) << 10) | t] =
                    *(ushort4*)pk;
            }
        }
}

// ---------------------------------------------------------------------------
// Fused MFMA flash attention — 32x32 quadrant structure, EXACT R4 version
// (measured best: total 124.6us). R5's gl_lds16 DMA staging regressed +4us:
// the barrier's vmcnt(0) gates on same-iteration DMA completion and the DMA
// LDS writes contend with frag reads mid-iteration (m151's DMA>reg result is
// throughput-regime, not this latency-bound convoy — regime mismatch).
// Structure: swapped QK^T (lane-local softmax), cvt_pk + permlane32 P->A
// frags (no LDS round-trip), reg-staged double-buffered K/V ([72]-padded),
// hoisted LDS loads, softmax/PV interleave, setprio around MFMA cluster,
// LDS qdot ring [j&255][s] with b64 refresh writes, one barrier per K-tile.
// Grid: x = bh (XCD L2 locality), y = s0/64. LDS = 73,728 B -> 2 blocks/CU.
// ---------------------------------------------------------------------------
__global__ __launch_bounds__(256)
void attn_mfma(const u16* __restrict__ qtb, const u16* __restrict__ ktb,
               const u16* __restrict__ vtb, const u16* __restrict__ pembb,
               __bf16* __restrict__ ctxb) {
    __shared__ __align__(16) __bf16 Kb[2][64][72];  // K tiles [t][d]
    __shared__ __align__(16) __bf16 Vb[2][64][72];  // V tiles [d][t]
    __shared__ __align__(16) __bf16 Qd[256][72];    // qdot ring [j&255][s]

    const int tid = threadIdx.x, w = tid >> 6, lane = tid & 63;
    const int l31 = lane & 31, hi = lane >> 5;
    const int wq = w >> 1, wt = w & 1;
    const int bh = blockIdx.x, b = bh >> 3;
    const int s0 = blockIdx.y * 64;

    // Q frags (B-operand for swapped QK^T, A-operand for ring refresh)
    bf8 qb[4];
    {
        const u16* qp = qtb + ((size_t)bh * SEQ + s0 + wq * 32 + l31) * HD + hi * 8;
        #pragma unroll
        for (int st = 0; st < 4; st++) qb[st] = *(const bf8*)(qp + st * 16);
    }

    // ---- init ring: j in [s0+449, +127], wave covers (s=wq-half, j=wt-half)
    #pragma unroll
    for (int pass = 0; pass < 2; pass++) {
        const int jr = s0 + 449 + pass * 64 + wt * 32 + l31;
        const int jc = min(1024, max(0, jr));
        const u16* pp = pembb + (size_t)jc * HD + hi * 8;
        f16v acc;
        #pragma unroll
        for (int r = 0; r < 16; r++) acc[r] = 0.f;
        #pragma unroll
        for (int st = 0; st < 4; st++) {
            bf8 pj = *(const bf8*)(pp + st * 16);
            acc = MFMA32(qb[st], pj, acc);
        }
        #pragma unroll
        for (int o4 = 0; o4 < 4; o4++) {
            bf4 pk;
            #pragma unroll
            for (int r = 0; r < 4; r++) pk[r] = (__bf16)acc[o4 * 4 + r];
            *(bf4*)&Qd[jr & 255][wq * 32 + o4 * 8 + hi * 4] = pk;
        }
    }

    float l_lane = 0.f;
    f16v oo[2];
    #pragma unroll
    for (int dt = 0; dt < 2; dt++)
        #pragma unroll
        for (int r = 0; r < 16; r++) oo[dt][r] = 0.f;

    const u16* kbase = ktb + (size_t)bh * SEQ * HD;   // [t][d] packed
    const u16* vbase = vtb + (size_t)bh * HD * SEQ;   // [d][t]
    const int sr = tid >> 3, sc = (tid & 7) * 8;

    // ---- stage tile 0 into buf 0 ----
    *(bf8*)&Kb[0][sr][sc]      = *(const bf8*)(kbase + (size_t)sr * HD + sc);
    *(bf8*)&Kb[0][sr + 32][sc] = *(const bf8*)(kbase + (size_t)(sr + 32) * HD + sc);
    *(bf8*)&Vb[0][sr][sc]      = *(const bf8*)(vbase + (size_t)sr * SEQ + sc);
    *(bf8*)&Vb[0][sr + 32][sc] = *(const bf8*)(vbase + (size_t)(sr + 32) * SEQ + sc);
    __syncthreads();

    for (int i = 0; i < 16; i++) {
        const int cur = i & 1, nxt = cur ^ 1;
        const int t0 = i * 64, t1 = t0 + 64;
        const bool pre = (i < 15);
        bf8 kr0, kr1, vr0, vr1, pj0, pj1, pj2, pj3;
        const int jrn = s0 + 449 - 64 * (i + 1) + wt * 32 + l31;
        if (pre) {
            kr0 = *(const bf8*)(kbase + (size_t)(t1 + sr) * HD + sc);
            kr1 = *(const bf8*)(kbase + (size_t)(t1 + sr + 32) * HD + sc);
            vr0 = *(const bf8*)(vbase + (size_t)sr * SEQ + t1 + sc);
            vr1 = *(const bf8*)(vbase + (size_t)(sr + 32) * SEQ + t1 + sc);
            const int jc = min(1024, max(0, jrn));
            const u16* pp = pembb + (size_t)jc * HD + hi * 8;
            pj0 = *(const bf8*)(pp);
            pj1 = *(const bf8*)(pp + 16);
            pj2 = *(const bf8*)(pp + 32);
            pj3 = *(const bf8*)(pp + 48);
        }

        // ---- ALL LDS loads up front: K-frags, ring gather, V-frags ----
        bf8 ka[4];
        #pragma unroll
        for (int st = 0; st < 4; st++)
            ka[st] = *(const bf8*)&Kb[cur][wt * 32 + l31][st * 16 + hi * 8];
        const int jcst = (s0 - t0 + 512) + wq * 32 + l31 - wt * 32 - 4 * hi;
        const u16* qdc = (const u16*)&Qd[0][0] + wq * 32 + l31;
        u16 rg[16];
        #pragma unroll
        for (int r = 0; r < 16; r++) {
            const int pat = (r & 3) + 8 * (r >> 2);
            rg[r] = qdc[((jcst - pat) & 255) * 72];
        }
        bf8 vf00 = *(const bf8*)&Vb[cur][l31][wt * 32 + hi * 8];
        bf8 vf01 = *(const bf8*)&Vb[cur][l31][wt * 32 + 16 + hi * 8];
        bf8 vf10 = *(const bf8*)&Vb[cur][32 + l31][wt * 32 + hi * 8];
        bf8 vf11 = *(const bf8*)&Vb[cur][32 + l31][wt * 32 + 16 + hi * 8];

        __builtin_amdgcn_s_setprio(1);
        // ---- QK^T, swapped: lane holds q = wq*32+l31, 16 t's of wt-half ----
        f16v s16;
        #pragma unroll
        for (int r = 0; r < 16; r++) s16[r] = 0.f;
        #pragma unroll
        for (int st = 0; st < 4; st++) s16 = MFMA32(ka[st], qb[st], s16);

        // ---- softmax half 0 -> pa0 -> 2 PV MFMAs ----
        float p[16];
        float la = 0.f, lb = 0.f;
        #pragma unroll
        for (int r = 0; r < 8; r++) {
            float pv = fexp2(s16[r] + b2f(rg[r]));
            p[r] = pv; la += pv;
        }
        unsigned w00 = cvtpk_bf16(p[0], p[1]), w01 = cvtpk_bf16(p[2], p[3]);
        unsigned w10 = cvtpk_bf16(p[4], p[5]), w11 = cvtpk_bf16(p[6], p[7]);
        swap32(w00, w10); swap32(w01, w11);
        union { unsigned u[4]; bf8 v; } pa0, pa1;
        pa0.u[0] = w00; pa0.u[1] = w01; pa0.u[2] = w10; pa0.u[3] = w11;
        oo[0] = MFMA32(pa0.v, vf00, oo[0]);
        oo[1] = MFMA32(pa0.v, vf10, oo[1]);
        // ---- softmax half 1 -> pa1 -> 2 PV MFMAs ----
        #pragma unroll
        for (int r = 8; r < 16; r++) {
            float pv = fexp2(s16[r] + b2f(rg[r]));
            p[r] = pv; lb += pv;
        }
        unsigned w20 = cvtpk_bf16(p[8],  p[9]),  w21 = cvtpk_bf16(p[10], p[11]);
        unsigned w30 = cvtpk_bf16(p[12], p[13]), w31 = cvtpk_bf16(p[14], p[15]);
        swap32(w20, w30); swap32(w21, w31);
        pa1.u[0] = w20; pa1.u[1] = w21; pa1.u[2] = w30; pa1.u[3] = w31;
        oo[0] = MFMA32(pa1.v, vf01, oo[0]);
        oo[1] = MFMA32(pa1.v, vf11, oo[1]);
        __builtin_amdgcn_s_setprio(0);
        l_lane += la + lb;

        // ---- ring refresh for next window (pemb frags already in regs) ----
        if (pre) {
            f16v rf;
            #pragma unroll
            for (int r = 0; r < 16; r++) rf[r] = 0.f;
            rf = MFMA32(qb[0], pj0, rf);
            rf = MFMA32(qb[1], pj1, rf);
            rf = MFMA32(qb[2], pj2, rf);
            rf = MFMA32(qb[3], pj3, rf);
            #pragma unroll
            for (int o4 = 0; o4 < 4; o4++) {
                bf4 pk;
                #pragma unroll
                for (int r = 0; r < 4; r++) pk[r] = (__bf16)rf[o4 * 4 + r];
                *(bf4*)&Qd[jrn & 255][wq * 32 + o4 * 8 + hi * 4] = pk;
            }
            // ---- commit prefetched K/V tile to buf nxt ----
            *(bf8*)&Kb[nxt][sr][sc]      = kr0;
            *(bf8*)&Kb[nxt][sr + 32][sc] = kr1;
            *(bf8*)&Vb[nxt][sr][sc]      = vr0;
            *(bf8*)&Vb[nxt][sr + 32][sc] = vr1;
        }
        __syncthreads();   // single barrier: staging visible, buffers released
    }

    // ---- epilogue: cross-half l, cross-wave O reduce (ring LDS reused),
    //      normalize, store ----
    float lsum = l_lane + __shfl_xor(l_lane, 32);
    float* Os = (float*)&Qd[0][0];          // ring is dead; reuse as scratch
    float* Ls = Os + 4096;
    if (lane < 32) Ls[(wq * 2 + wt) * 32 + l31] = lsum;
    if (wt == 0) {
        #pragma unroll
        for (int dt = 0; dt < 2; dt++)
            #pragma unroll
            for (int r = 0; r < 16; r++) {
                const int q = (r & 3) + 8 * (r >> 2) + 4 * hi;
                Os[(wq * 32 + q) * 64 + dt * 32 + l31] = oo[dt][r];
            }
    }
    __syncthreads();
    if (wt == 1) {
        const int h = bh & 7;
        #pragma unroll
        for (int r = 0; r < 16; r++) {
            const int q = (r & 3) + 8 * (r >> 2) + 4 * hi;
            const float li = 1.f / (Ls[wq * 64 + q] + Ls[wq * 64 + 32 + q]);
            #pragma unroll
            for (int dt = 0; dt < 2; dt++) {
                float v = (oo[dt][r] + Os[(wq * 32 + q) * 64 + dt * 32 + l31]) * li;
                ctxb[(size_t)(b * SEQ + s0 + wq * 32 + q) * DM + h * HD + dt * 32 + l31]
                    = (__bf16)v;
            }
        }
    }
}

// ---------------------------------------------------------------------------
extern "C" void kernel_launch(void* const* d_in, const int* in_sizes, int n_in,
                              void* d_out, int out_size, void* d_ws, size_t ws_size,
                              hipStream_t stream) {
    const float* x    = (const float*)d_in[0];
    // d_in[1] attn_mask: unused by the reference computation
    const float* Wq   = (const float*)d_in[2];
    const float* Wkv  = (const float*)d_in[3];
    const float* Wout = (const float*)d_in[4];
    const float* bout = (const float*)d_in[5];
    const float* pemb = (const float*)d_in[6];
    float* out = (float*)d_out;

    const int M = BATCH * SEQ;   // 4096
    u16* p = (u16*)d_ws;
    u16* xb    = p; p += (size_t)M * DM;          // 4096x512
    u16* qkvw  = p; p += (size_t)NQKV * DM;       // 1536x512 (Wq^T ++ Wkv^T)
    u16* Woutt = p; p += (size_t)DM * DM;         // 512x512
    u16* pembb = p; p += (size_t)1025 * HD;       // 1025x64
    u16* qtb   = p; p += (size_t)M * DM;          // 32x1024x64 packed q (scaled)
    u16* ktb   = p; p += (size_t)M * DM;          // 32x1024x64 packed K
    u16* vtb   = p; p += (size_t)M * DM;          // 32x64x1024 transposed V
    u16* ctxb  = p; p += (size_t)M * DM;          // 4096x512

    prep<<<3137, 256, 0, stream>>>(x, Wq, Wkv, Wout, pemb, xb, qkvw, Woutt, pembb);

    // QKV projection with fused q-scale / K-pack / V-transpose epilogue
    // BN=192: 8x64 = 512 blocks = 2/CU, 1.5x arithmetic intensity vs BN=128
    gemm_bt<192><<<dim3(NQKV / 192, M / 64), 256, 0, stream>>>(
        xb, qkvw, M, NQKV, DM, nullptr, nullptr,
        (__bf16*)qtb, (__bf16*)ktb, (__bf16*)vtb);

    // fused attention -> ctx; grid x=bh for XCD L2 locality
    attn_mfma<<<dim3(BATCH * NH, SEQ / 64), 256, 0, stream>>>(
        qtb, ktb, vtb, pembb, (__bf16*)ctxb);

    // out = ctx @ Wout + bout  (BN=64: 512 blocks = 2/CU vs 1/CU at BN=128)
    gemm_bt<64><<<dim3(DM / 64, M / 64), 256, 0, stream>>>(
        ctxb, Woutt, M, DM, DM, out, bout, nullptr, nullptr, nullptr);
}

// Round 7
// 124.262 us; speedup vs baseline: 1.0344x; 1.0137x over previous
//
#include <hip/hip_runtime.h>
#include <hip/hip_bf16.h>

constexpr int BATCH = 4;
constexpr int SEQ   = 1024;
constexpr int DM    = 512;     // model dim = HEADS*HDIM
constexpr int NH    = 8;
constexpr int HD    = 64;
constexpr int NQKV  = 1536;    // q(512) + k(512) + v(512) fused projection width

typedef unsigned short u16;
typedef __attribute__((ext_vector_type(8))) __bf16 bf8;
typedef __attribute__((ext_vector_type(4))) __bf16 bf4;
typedef __attribute__((ext_vector_type(4))) float  f4;
typedef __attribute__((ext_vector_type(16))) float f16v;

#define MFMA16(a, b, c) __builtin_amdgcn_mfma_f32_16x16x32_bf16(a, b, c, 0, 0, 0)
#define MFMA32(a, b, c) __builtin_amdgcn_mfma_f32_32x32x16_bf16(a, b, c, 0, 0, 0)

// 0.125 (1/sqrt(64)) * log2(e): q pre-scale so softmax uses exp2 directly
#define QSC 0.18033688f

static __device__ __forceinline__ u16 f2b(float f) {
    union { float f; unsigned u; } v; v.f = f;
    unsigned r = v.u + 0x7FFFu + ((v.u >> 16) & 1u);   // RNE; inputs never NaN
    return (u16)(r >> 16);
}
static __device__ __forceinline__ float b2f(u16 x) {
    union { unsigned u; float f; } v; v.u = (unsigned)x << 16;   // bf16->f32 exact
    return v.f;
}
static __device__ __forceinline__ float fexp2(float x) {
    return __builtin_amdgcn_exp2f(x);
}
// async global->LDS, 16 B per lane (dst = wave-uniform base + lane*16)
static __device__ __forceinline__ void gl_lds16(const void* g, void* l) {
    __builtin_amdgcn_global_load_lds(
        (const __attribute__((address_space(1))) void*)g,
        (__attribute__((address_space(3))) void*)l, 16, 0, 0);
}
// pack two f32 -> one u32 of 2 bf16 (RNE), single VOP3
static __device__ __forceinline__ unsigned cvtpk_bf16(float lo, float hi) {
    unsigned r;
    asm("v_cvt_pk_bf16_f32 %0, %1, %2" : "=v"(r) : "v"(lo), "v"(hi));
    return r;
}
// swap a's hi-32-lane half with b's lo-32-lane half
static __device__ __forceinline__ void swap32(unsigned &a, unsigned &b) {
    asm("v_permlane32_swap_b32 %0, %1" : "+v"(a), "+v"(b));
}

// ---------------------------------------------------------------------------
// Fused prep: one launch does all fp32->bf16 converts + weight transposes.
// ---------------------------------------------------------------------------
__device__ __forceinline__ void tcvt_tile(const float* __restrict__ in,
                                          u16* __restrict__ out,
                                          int R, int C, int bx, int by, int tid,
                                          float (*t)[33]) {
    int r0 = by * 32, c0 = bx * 32;
    int lc = tid & 31, lr = tid >> 5;   // lr in [0,8)
    #pragma unroll
    for (int p = 0; p < 4; p++) {
        int r = lr + p * 8;
        t[r][lc] = in[(size_t)(r0 + r) * C + c0 + lc];
    }
    __syncthreads();
    #pragma unroll
    for (int p = 0; p < 4; p++) {
        int r = lr + p * 8;
        out[(size_t)(c0 + r) * R + r0 + lc] = f2b(t[lc][r]);
    }
}

__global__ __launch_bounds__(256)
void prep(const float* __restrict__ x, const float* __restrict__ Wq,
          const float* __restrict__ Wkv, const float* __restrict__ Wout,
          const float* __restrict__ pemb,
          u16* __restrict__ xb, u16* __restrict__ qkvw,
          u16* __restrict__ Woutt, u16* __restrict__ pembb) {
    __shared__ float t[32][33];
    const int blk = blockIdx.x, tid = threadIdx.x;
    if (blk < 2048) {
        int i = (blk * 256 + tid) * 4;
        float4 v = *(const float4*)(x + i);
        ushort4 o = {f2b(v.x), f2b(v.y), f2b(v.z), f2b(v.w)};
        *(ushort4*)(xb + i) = o;
    } else if (blk < 2113) {
        int i = ((blk - 2048) * 256 + tid) * 4;
        if (i < 1025 * HD) {
            float4 v = *(const float4*)(pemb + i);
            ushort4 o = {f2b(v.x), f2b(v.y), f2b(v.z), f2b(v.w)};
            *(ushort4*)(pembb + i) = o;
        }
    } else if (blk < 2369) {
        int l = blk - 2113;
        tcvt_tile(Wq, qkvw, 512, 512, l & 15, l >> 4, tid, t);
    } else if (blk < 2881) {
        int l = blk - 2369;
        tcvt_tile(Wkv, qkvw + 512 * 512, 512, 1024, l & 31, l >> 5, tid, t);
    } else {
        int l = blk - 2881;
        tcvt_tile(Wout, Woutt, 512, 512, l & 15, l >> 4, tid, t);
    }
}

// ---------------------------------------------------------------------------
// MFMA GEMM: C[M,N] = A[M,K] @ Bt[N,K]^T  (bf16 in, fp32 acc)
// Templated on BN (tile = 64 x BN). BK=64 as 2x 32-wide sub-tiles (m97
// layout). 256 threads = 4 waves; per-wave output 32 x BN/2.
//   BN=128: QKV projection (R6 showed BN=192 neutral-to-worse; reverted).
//   BN=64:  output projection — 512 blocks = 2/CU (was 1/CU at BN=128).
// Mode 1 (Cf!=null): fp32 out + bias. Mode 2 (qtb/ktb/vtb): QKV packing.
// ---------------------------------------------------------------------------
template<int BN>
__global__ __launch_bounds__(256)
void gemm_bt(const u16* __restrict__ A, const u16* __restrict__ Bt,
             int M, int N, int K,
             float* __restrict__ Cf, const float* __restrict__ bias,
             __bf16* __restrict__ qtb, __bf16* __restrict__ ktb,
             __bf16* __restrict__ vtb) {
    constexpr int NJ = BN / 32;          // B-frags per wave
    __shared__ __align__(16) u16 As[2][64][32];
    __shared__ __align__(16) u16 Bs[2][BN][32];
    const int tid = threadIdx.x, w = tid >> 6, lane = tid & 63;
    const int l15 = lane & 15, l4 = lane >> 4;
    const int wr = (w >> 1) * 32, wc = (w & 1) * (BN / 2);
    const int bm = blockIdx.y * 64, bn = blockIdx.x * BN;

    f4 acc[2][NJ];
    #pragma unroll
    for (int i = 0; i < 2; i++)
        #pragma unroll
        for (int j = 0; j < NJ; j++) acc[i][j] = (f4){0.f, 0.f, 0.f, 0.f};

    const int rS = lane >> 2;          // row within a 16-row staging group
    const int cS = (lane & 3) * 8;     // col (u16) within the 32-wide row

    for (int k0 = 0; k0 < K; k0 += 64) {
        #pragma unroll
        for (int ks = 0; ks < 2; ks++) {
            // A: sub-tile ks, rows [w*16, +16)
            gl_lds16(A + (size_t)(bm + w * 16 + rS) * K + k0 + ks * 32 + cS,
                     &As[ks][w * 16][0]);
            // B: sub-tile ks, BN/4 rows per wave in 16-row groups
            #pragma unroll
            for (int rb = 0; rb < BN / 4; rb += 16)
                gl_lds16(Bt + (size_t)(bn + w * (BN / 4) + rb + rS) * K
                             + k0 + ks * 32 + cS,
                         &Bs[ks][w * (BN / 4) + rb][0]);
        }
        __syncthreads();
        #pragma unroll
        for (int ks = 0; ks < 2; ks++) {
            bf8 af[2], bf[NJ];
            #pragma unroll
            for (int i = 0; i < 2; i++)
                af[i] = *(const bf8*)&As[ks][wr + i * 16 + l15][l4 * 8];
            #pragma unroll
            for (int j = 0; j < NJ; j++)
                bf[j] = *(const bf8*)&Bs[ks][wc + j * 16 + l15][l4 * 8];
            #pragma unroll
            for (int i = 0; i < 2; i++)
                #pragma unroll
                for (int j = 0; j < NJ; j++)
                    acc[i][j] = MFMA16(af[i], bf[j], acc[i][j]);
        }
        __syncthreads();
    }
    #pragma unroll
    for (int i = 0; i < 2; i++)
        #pragma unroll
        for (int j = 0; j < NJ; j++) {
            const int col = bn + wc + j * 16 + l15;
            const int row0 = bm + wr + i * 16 + l4 * 4;
            if (Cf) {
                #pragma unroll
                for (int reg = 0; reg < 4; reg++)
                    Cf[(size_t)(row0 + reg) * N + col] = acc[i][j][reg] + bias[col];
            } else if (col < 512) {
                int h = col >> 6, d = col & 63;
                #pragma unroll
                for (int reg = 0; reg < 4; reg++) {
                    int row = row0 + reg;
                    int b = row >> 10, t = row & 1023;
                    qtb[((((size_t)(b * 8 + h)) << 10 | t) << 6) | d] =
                        (__bf16)(acc[i][j][reg] * QSC);
                }
            } else if (col < 1024) {
                int h = (col >> 6) - 8, d = col & 63;
                #pragma unroll
                for (int reg = 0; reg < 4; reg++) {
                    int row = row0 + reg;
                    int b = row >> 10, t = row & 1023;
                    ktb[((((size_t)(b * 8 + h)) << 10 | t) << 6) | d] =
                        (__bf16)acc[i][j][reg];
                }
            } else {
                int h = (col >> 6) - 16, d = col & 63;
                int b = row0 >> 10, t = row0 & 1023;   // 4 rows share b (t aligned 4)
                __bf16 pk[4];
                #pragma unroll
                for (int reg = 0; reg < 4; reg++) pk[reg] = (__bf16)acc[i][j][reg];
                *(ushort4*)&vtb[(((size_t)(b * 8 + h) * 64 + d) << 10) | t] =
                    *(ushort4*)pk;
            }
        }
}

// ---------------------------------------------------------------------------
// Fused MFMA flash attention — 32x32 quadrant structure (R4 base) + tail
// de-convoy (R7). Pipe accounting says no pipe >~50% busy -> bound by the
// barrier-locked chain, specifically the pre-barrier TAIL (PV1 -> refresh
// dep-chain -> ring writes -> K/V commits -> barrier), which no co-resident
// wave can hide. R7 scheduling edits (no structural change):
//  - K/V commits moved MID-iteration (after PV0): vmcnt distance from the
//    top-of-iter global loads is ~QK^T+sm0 (~400cy, warm-L2 OK), and the
//    ds_writes overlap sm-half1 VALU instead of the tail. Legal: [nxt] was
//    released at the PREVIOUS barrier; all [cur] reads are textually earlier.
//  - Refresh MFMA chain starts right after the commit (under sm1/PV1);
//    only the 4 ring b64 writes remain on the tail.
//  - setprio(1) narrowed to the MFMA clusters (QK^T/PV0/PV1) — prio-1 during
//    our softmax VALU starved the other block's MFMA waves (HK wraps mma only).
// Grid: x = bh (XCD L2 locality), y = s0/64. LDS = 73,728 B -> 2 blocks/CU.
// ---------------------------------------------------------------------------
__global__ __launch_bounds__(256)
void attn_mfma(const u16* __restrict__ qtb, const u16* __restrict__ ktb,
               const u16* __restrict__ vtb, const u16* __restrict__ pembb,
               __bf16* __restrict__ ctxb) {
    __shared__ __align__(16) __bf16 Kb[2][64][72];  // K tiles [t][d]
    __shared__ __align__(16) __bf16 Vb[2][64][72];  // V tiles [d][t]
    __shared__ __align__(16) __bf16 Qd[256][72];    // qdot ring [j&255][s]

    const int tid = threadIdx.x, w = tid >> 6, lane = tid & 63;
    const int l31 = lane & 31, hi = lane >> 5;
    const int wq = w >> 1, wt = w & 1;
    const int bh = blockIdx.x, b = bh >> 3;
    const int s0 = blockIdx.y * 64;

    // Q frags (B-operand for swapped QK^T, A-operand for ring refresh)
    bf8 qb[4];
    {
        const u16* qp = qtb + ((size_t)bh * SEQ + s0 + wq * 32 + l31) * HD + hi * 8;
        #pragma unroll
        for (int st = 0; st < 4; st++) qb[st] = *(const bf8*)(qp + st * 16);
    }

    // ---- init ring: j in [s0+449, +127], wave covers (s=wq-half, j=wt-half)
    #pragma unroll
    for (int pass = 0; pass < 2; pass++) {
        const int jr = s0 + 449 + pass * 64 + wt * 32 + l31;
        const int jc = min(1024, max(0, jr));
        const u16* pp = pembb + (size_t)jc * HD + hi * 8;
        f16v acc;
        #pragma unroll
        for (int r = 0; r < 16; r++) acc[r] = 0.f;
        #pragma unroll
        for (int st = 0; st < 4; st++) {
            bf8 pj = *(const bf8*)(pp + st * 16);
            acc = MFMA32(qb[st], pj, acc);
        }
        #pragma unroll
        for (int o4 = 0; o4 < 4; o4++) {
            bf4 pk;
            #pragma unroll
            for (int r = 0; r < 4; r++) pk[r] = (__bf16)acc[o4 * 4 + r];
            *(bf4*)&Qd[jr & 255][wq * 32 + o4 * 8 + hi * 4] = pk;
        }
    }

    float l_lane = 0.f;
    f16v oo[2];
    #pragma unroll
    for (int dt = 0; dt < 2; dt++)
        #pragma unroll
        for (int r = 0; r < 16; r++) oo[dt][r] = 0.f;

    const u16* kbase = ktb + (size_t)bh * SEQ * HD;   // [t][d] packed
    const u16* vbase = vtb + (size_t)bh * HD * SEQ;   // [d][t]
    const int sr = tid >> 3, sc = (tid & 7) * 8;

    // ---- stage tile 0 into buf 0 ----
    *(bf8*)&Kb[0][sr][sc]      = *(const bf8*)(kbase + (size_t)sr * HD + sc);
    *(bf8*)&Kb[0][sr + 32][sc] = *(const bf8*)(kbase + (size_t)(sr + 32) * HD + sc);
    *(bf8*)&Vb[0][sr][sc]      = *(const bf8*)(vbase + (size_t)sr * SEQ + sc);
    *(bf8*)&Vb[0][sr + 32][sc] = *(const bf8*)(vbase + (size_t)(sr + 32) * SEQ + sc);
    __syncthreads();

    for (int i = 0; i < 16; i++) {
        const int cur = i & 1, nxt = cur ^ 1;
        const int t0 = i * 64, t1 = t0 + 64;
        const bool pre = (i < 15);
        bf8 kr0, kr1, vr0, vr1, pj0, pj1, pj2, pj3;
        const int jrn = s0 + 449 - 64 * (i + 1) + wt * 32 + l31;
        if (pre) {
            kr0 = *(const bf8*)(kbase + (size_t)(t1 + sr) * HD + sc);
            kr1 = *(const bf8*)(kbase + (size_t)(t1 + sr + 32) * HD + sc);
            vr0 = *(const bf8*)(vbase + (size_t)sr * SEQ + t1 + sc);
            vr1 = *(const bf8*)(vbase + (size_t)(sr + 32) * SEQ + t1 + sc);
            const int jc = min(1024, max(0, jrn));
            const u16* pp = pembb + (size_t)jc * HD + hi * 8;
            pj0 = *(const bf8*)(pp);
            pj1 = *(const bf8*)(pp + 16);
            pj2 = *(const bf8*)(pp + 32);
            pj3 = *(const bf8*)(pp + 48);
        }

        // ---- ALL LDS loads up front: K-frags, ring gather, V-frags ----
        bf8 ka[4];
        #pragma unroll
        for (int st = 0; st < 4; st++)
            ka[st] = *(const bf8*)&Kb[cur][wt * 32 + l31][st * 16 + hi * 8];
        const int jcst = (s0 - t0 + 512) + wq * 32 + l31 - wt * 32 - 4 * hi;
        const u16* qdc = (const u16*)&Qd[0][0] + wq * 32 + l31;
        u16 rg[16];
        #pragma unroll
        for (int r = 0; r < 16; r++) {
            const int pat = (r & 3) + 8 * (r >> 2);
            rg[r] = qdc[((jcst - pat) & 255) * 72];
        }
        bf8 vf00 = *(const bf8*)&Vb[cur][l31][wt * 32 + hi * 8];
        bf8 vf01 = *(const bf8*)&Vb[cur][l31][wt * 32 + 16 + hi * 8];
        bf8 vf10 = *(const bf8*)&Vb[cur][32 + l31][wt * 32 + hi * 8];
        bf8 vf11 = *(const bf8*)&Vb[cur][32 + l31][wt * 32 + 16 + hi * 8];

        // ---- QK^T, swapped: lane holds q = wq*32+l31, 16 t's of wt-half ----
        __builtin_amdgcn_s_setprio(1);
        f16v s16;
        #pragma unroll
        for (int r = 0; r < 16; r++) s16[r] = 0.f;
        #pragma unroll
        for (int st = 0; st < 4; st++) s16 = MFMA32(ka[st], qb[st], s16);
        __builtin_amdgcn_s_setprio(0);

        // ---- softmax half 0 -> pa0 -> 2 PV MFMAs ----
        float p[16];
        float la = 0.f, lb = 0.f;
        #pragma unroll
        for (int r = 0; r < 8; r++) {
            float pv = fexp2(s16[r] + b2f(rg[r]));
            p[r] = pv; la += pv;
        }
        unsigned w00 = cvtpk_bf16(p[0], p[1]), w01 = cvtpk_bf16(p[2], p[3]);
        unsigned w10 = cvtpk_bf16(p[4], p[5]), w11 = cvtpk_bf16(p[6], p[7]);
        swap32(w00, w10); swap32(w01, w11);
        union { unsigned u[4]; bf8 v; } pa0, pa1;
        pa0.u[0] = w00; pa0.u[1] = w01; pa0.u[2] = w10; pa0.u[3] = w11;
        __builtin_amdgcn_s_setprio(1);
        oo[0] = MFMA32(pa0.v, vf00, oo[0]);
        oo[1] = MFMA32(pa0.v, vf10, oo[1]);
        __builtin_amdgcn_s_setprio(0);

        // ---- mid-iter commit of next K/V tile (off the pre-barrier tail;
        //      vmcnt distance from top-of-iter loads ~= QK^T + sm0) ----
        if (pre) {
            *(bf8*)&Kb[nxt][sr][sc]      = kr0;
            *(bf8*)&Kb[nxt][sr + 32][sc] = kr1;
            *(bf8*)&Vb[nxt][sr][sc]      = vr0;
            *(bf8*)&Vb[nxt][sr + 32][sc] = vr1;
        }
        // ---- refresh MFMA chain starts here, completes under sm1/PV1 ----
        f16v rf;
        if (pre) {
            #pragma unroll
            for (int r = 0; r < 16; r++) rf[r] = 0.f;
            rf = MFMA32(qb[0], pj0, rf);
            rf = MFMA32(qb[1], pj1, rf);
            rf = MFMA32(qb[2], pj2, rf);
            rf = MFMA32(qb[3], pj3, rf);
        }

        // ---- softmax half 1 -> pa1 -> 2 PV MFMAs ----
        #pragma unroll
        for (int r = 8; r < 16; r++) {
            float pv = fexp2(s16[r] + b2f(rg[r]));
            p[r] = pv; lb += pv;
        }
        unsigned w20 = cvtpk_bf16(p[8],  p[9]),  w21 = cvtpk_bf16(p[10], p[11]);
        unsigned w30 = cvtpk_bf16(p[12], p[13]), w31 = cvtpk_bf16(p[14], p[15]);
        swap32(w20, w30); swap32(w21, w31);
        pa1.u[0] = w20; pa1.u[1] = w21; pa1.u[2] = w30; pa1.u[3] = w31;
        __builtin_amdgcn_s_setprio(1);
        oo[0] = MFMA32(pa1.v, vf01, oo[0]);
        oo[1] = MFMA32(pa1.v, vf11, oo[1]);
        __builtin_amdgcn_s_setprio(0);
        l_lane += la + lb;

        // ---- tail: only the ring b64 writes remain ----
        if (pre) {
            #pragma unroll
            for (int o4 = 0; o4 < 4; o4++) {
                bf4 pk;
                #pragma unroll
                for (int r = 0; r < 4; r++) pk[r] = (__bf16)rf[o4 * 4 + r];
                *(bf4*)&Qd[jrn & 255][wq * 32 + o4 * 8 + hi * 4] = pk;
            }
        }
        __syncthreads();   // single barrier: staging visible, buffers released
    }

    // ---- epilogue: cross-half l, cross-wave O reduce (ring LDS reused),
    //      normalize, store ----
    float lsum = l_lane + __shfl_xor(l_lane, 32);
    float* Os = (float*)&Qd[0][0];          // ring is dead; reuse as scratch
    float* Ls = Os + 4096;
    if (lane < 32) Ls[(wq * 2 + wt) * 32 + l31] = lsum;
    if (wt == 0) {
        #pragma unroll
        for (int dt = 0; dt < 2; dt++)
            #pragma unroll
            for (int r = 0; r < 16; r++) {
                const int q = (r & 3) + 8 * (r >> 2) + 4 * hi;
                Os[(wq * 32 + q) * 64 + dt * 32 + l31] = oo[dt][r];
            }
    }
    __syncthreads();
    if (wt == 1) {
        const int h = bh & 7;
        #pragma unroll
        for (int r = 0; r < 16; r++) {
            const int q = (r & 3) + 8 * (r >> 2) + 4 * hi;
            const float li = 1.f / (Ls[wq * 64 + q] + Ls[wq * 64 + 32 + q]);
            #pragma unroll
            for (int dt = 0; dt < 2; dt++) {
                float v = (oo[dt][r] + Os[(wq * 32 + q) * 64 + dt * 32 + l31]) * li;
                ctxb[(size_t)(b * SEQ + s0 + wq * 32 + q) * DM + h * HD + dt * 32 + l31]
                    = (__bf16)v;
            }
        }
    }
}

// ---------------------------------------------------------------------------
extern "C" void kernel_launch(void* const* d_in, const int* in_sizes, int n_in,
                              void* d_out, int out_size, void* d_ws, size_t ws_size,
                              hipStream_t stream) {
    const float* x    = (const float*)d_in[0];
    // d_in[1] attn_mask: unused by the reference computation
    const float* Wq   = (const float*)d_in[2];
    const float* Wkv  = (const float*)d_in[3];
    const float* Wout = (const float*)d_in[4];
    const float* bout = (const float*)d_in[5];
    const float* pemb = (const float*)d_in[6];
    float* out = (float*)d_out;

    const int M = BATCH * SEQ;   // 4096
    u16* p = (u16*)d_ws;
    u16* xb    = p; p += (size_t)M * DM;          // 4096x512
    u16* qkvw  = p; p += (size_t)NQKV * DM;       // 1536x512 (Wq^T ++ Wkv^T)
    u16* Woutt = p; p += (size_t)DM * DM;         // 512x512
    u16* pembb = p; p += (size_t)1025 * HD;       // 1025x64
    u16* qtb   = p; p += (size_t)M * DM;          // 32x1024x64 packed q (scaled)
    u16* ktb   = p; p += (size_t)M * DM;          // 32x1024x64 packed K
    u16* vtb   = p; p += (size_t)M * DM;          // 32x64x1024 transposed V
    u16* ctxb  = p; p += (size_t)M * DM;          // 4096x512

    prep<<<3137, 256, 0, stream>>>(x, Wq, Wkv, Wout, pemb, xb, qkvw, Woutt, pembb);

    // QKV projection with fused q-scale / K-pack / V-transpose epilogue
    gemm_bt<128><<<dim3(NQKV / 128, M / 64), 256, 0, stream>>>(
        xb, qkvw, M, NQKV, DM, nullptr, nullptr,
        (__bf16*)qtb, (__bf16*)ktb, (__bf16*)vtb);

    // fused attention -> ctx; grid x=bh for XCD L2 locality
    attn_mfma<<<dim3(BATCH * NH, SEQ / 64), 256, 0, stream>>>(
        qtb, ktb, vtb, pembb, (__bf16*)ctxb);

    // out = ctx @ Wout + bout  (BN=64: 512 blocks = 2/CU vs 1/CU at BN=128)
    gemm_bt<64><<<dim3(DM / 64, M / 64), 256, 0, stream>>>(
        ctxb, Woutt, M, DM, DM, out, bout, nullptr, nullptr, nullptr);
}